// Round 5
// baseline (308.765 us; speedup 1.0000x reference)
//
#include <hip/hip_runtime.h>
#include <cstdint>
#include <math.h>

// GREEN since r6. Ladder: r15 490 -> r17 326 (v_pk_fma_f32 PROVEN full-rate
// on gfx950) -> r19 285 (DPP butterfly m=1..8 + Un off LDS).
// COUNTER FORENSICS (r19): VGPR_Count=120 proves U was NEVER register-
// resident in any round -- the compiler rematerializes the loop-invariant
// U loads INSIDE the step loop (~192 VMEM + ~350 addr-calc VALU per step,
// the bulk of VALUBusy=73%). r14's AGPR disaster was this plus AGPR chains.
// THIS ROUND r20: force TRUE residency with an empty asm keep-alive
// ("+v" on all 12 v16f U blocks) at the top of each iteration. The asm
// "modifies" them -> rematerialization becomes illegal -> 192 U floats
// pinned in VGPRs. Budget: 192 + ~50 live ~= 242 <= 256 (keeps 2 waves/
// SIMD; waves halve at ~256). Zero emitted instructions; arithmetic, FMA
// order, PRNG identical -> absmax must stay 0.0.
// Predict: VGPR ~240, dur 285 -> 200-230us. Failure: VGPR>=256 (1 wave/
// SIMD) or scratch spill -> pivot to 4-wave block with shared LDS U^T.
// EMPIRICAL RULES: only __launch_bounds__(64,1) gives the full reg budget
// ((64,2)->128 cap, r8 disaster); OccupancyPercent counter is gfx94x
// fallback (untrustworthy). Occupancy is grid-capped at 2 waves/SIMD.
// Locked-in: PRNG = partitionable threefry (key_t = tf((0,42),(0,t)); bits =
// o0^o1 of tf(key_t,(0,2s+cat))); f32 in/out; out = [4096*144][4096];
// decisions rounding-robust (6 arithmetic variants, bit-identical streams).

#define NSAMP 4096
#define NSTEP 144
#define HID 64
#define CPB 2            // chains per block (one wave)

typedef float v16f __attribute__((ext_vector_type(16)));
typedef float v4f  __attribute__((ext_vector_type(4)));
typedef float v2f  __attribute__((ext_vector_type(2)));

// ---- JAX threefry2x32 (20 rounds, key-inject every 4) ----
__device__ __forceinline__ void threefry2x32(uint32_t k0, uint32_t k1,
                                             uint32_t x0, uint32_t x1,
                                             uint32_t& o0, uint32_t& o1) {
  const uint32_t ks0 = k0, ks1 = k1, ks2 = k0 ^ k1 ^ 0x1BD11BDAu;
  x0 += ks0; x1 += ks1;
#define TF_ROUND(d) { x0 += x1; x1 = (x1 << (d)) | (x1 >> (32 - (d))); x1 ^= x0; }
  TF_ROUND(13) TF_ROUND(15) TF_ROUND(26) TF_ROUND(6)
  x0 += ks1; x1 += ks2 + 1u;
  TF_ROUND(17) TF_ROUND(29) TF_ROUND(16) TF_ROUND(24)
  x0 += ks2; x1 += ks0 + 2u;
  TF_ROUND(13) TF_ROUND(15) TF_ROUND(26) TF_ROUND(6)
  x0 += ks0; x1 += ks1 + 3u;
  TF_ROUND(17) TF_ROUND(29) TF_ROUND(16) TF_ROUND(24)
  x0 += ks1; x1 += ks2 + 4u;
  TF_ROUND(13) TF_ROUND(15) TF_ROUND(26) TF_ROUND(6)
  x0 += ks2; x1 += ks0 + 5u;
#undef TF_ROUND
  o0 = x0; o1 = x1;
}

// fast branch-free f32 transcendentals (raw v_exp_f32 / v_log_f32 / v_rcp_f32)
__device__ __forceinline__ float fsig(float x) {        // 1/(1+e^-x), stable
  return __builtin_amdgcn_rcpf(1.0f + __expf(-x));
}
__device__ __forceinline__ float ftanh(float x) {       // 1 - 2/(e^2x+1)
  const float e = __expf(2.0f * x);
  return 1.0f - 2.0f * __builtin_amdgcn_rcpf(e + 1.0f);
}

// Packed f32 FMA, chains (a,b) in (lo,hi). u-pair is an even-aligned register
// pair; LO variant broadcasts its low element to both halves, HI the high one.
#define PKFMA_LO(acc, h2, up) \
  asm("v_pk_fma_f32 %0, %1, %2, %0 op_sel_hi:[1,0,1]" \
      : "+v"(acc) : "v"(h2), "v"(up));
#define PKFMA_HI(acc, h2, up) \
  asm("v_pk_fma_f32 %0, %1, %2, %0 op_sel:[0,1,0] op_sel_hi:[1,1,1]" \
      : "+v"(acc) : "v"(h2), "v"(up));

// DPP butterfly level: v += lane-swapped(v). ctrl as template param (imm).
// Patterns bitwise-match __shfl_xor(v, m) given the uniformity at each level.
template <int CTRL>
__device__ __forceinline__ float dpp_add(float v) {
  union { float f; int i; } c; c.f = v;
  union { int i; float f; } r;
  r.i = __builtin_amdgcn_mov_dpp(c.i, CTRL, 0xF, 0xF, true);
  return v + r.f;
}
#define DPP_XOR1 0xB1   // quad_perm(1,0,3,2)
#define DPP_XOR2 0x4E   // quad_perm(2,3,0,1)
#define DPP_XOR4 0x141  // row_half_mirror (quad-uniform => == xor4)
#define DPP_XOR8 0x140  // row_mirror (8-uniform => == xor8)

__global__ __launch_bounds__(64, 1) void vmc_kernel(
    const float* __restrict__ W, const float* __restrict__ U,
    const float* __restrict__ B, const float* __restrict__ Wd,
    const float* __restrict__ Bd, float* __restrict__ out) {
  const int j = threadIdx.x;           // hidden unit owned by this lane
  const int s_base = blockIdx.x * CPB; // first of 2 chains in this block

  __shared__ __align__(16) float2 hsh2[HID];      // h[unit] = {chain a, chain b}
  __shared__ uint2 kkeys[NSTEP];
  __shared__ float gsh[CPB * 2 * NSTEP];          // gumbels [c*288 + 2t + cat]

  // --- per-step keys: key_t = threefry((0,42),(0,t)) ---
#pragma unroll 1
  for (int t = j; t < NSTEP; t += HID) {
    uint32_t o0, o1;
    threefry2x32(0u, 42u, 0u, (uint32_t)t, o0, o1);
    kkeys[t].x = o0; kkeys[t].y = o1;
  }
  hsh2[j] = float2{0.0f, 0.0f};
  __syncthreads();

  // --- gumbels: EXACT path kept (f64 libm, one-time): bits = o0^o1 of
  // tf(key_t,(0,2s+cat)); u = bitcast(bits>>9|0x3f800000)-1 clamped tiny ---
#pragma unroll 1
  for (int id = j; id < CPB * 2 * NSTEP; id += HID) {
    const int c = id / 288;
    const int idx = id - c * 288;
    const uint2 kt = kkeys[idx >> 1];
    const uint32_t i = 2u * (uint32_t)(s_base + c) + (uint32_t)(idx & 1);
    uint32_t o0, o1;
    threefry2x32(kt.x, kt.y, 0u, i, o0, o1);
    const uint32_t bits = o0 ^ o1;
    union { uint32_t u; float f; } cv; cv.u = (bits >> 9) | 0x3F800000u;
    float uf = cv.f - 1.0f;
    uf = fmaxf(uf, 1.17549435e-38f);
    const float inner = (float)log((double)uf);
    gsh[id] = -(float)log((double)(-inner));
  }
  __syncthreads();

  // --- Uz, Ur, Un columns for unit j: 192 floats, to be PINNED in VGPRs ---
  v16f uz0, uz1, uz2, uz3, ur0, ur1, ur2, ur3, un0, un1, un2, un3;
#define LOADB(v, r, off) \
  { _Pragma("unroll") for (int e = 0; e < 16; ++e) v[e] = U[((r)*16 + e)*192 + (off) + j]; }
  LOADB(uz0, 0, 0)    LOADB(uz1, 1, 0)    LOADB(uz2, 2, 0)    LOADB(uz3, 3, 0)
  LOADB(ur0, 0, 64)   LOADB(ur1, 1, 64)   LOADB(ur2, 2, 64)   LOADB(ur3, 3, 64)
  LOADB(un0, 0, 128)  LOADB(un1, 1, 128)  LOADB(un2, 2, 128)  LOADB(un3, 3, 128)
#undef LOADB

  const float b1z = B[192 + j], b1r = B[256 + j], b1n = B[320 + j];
  const float b0z = B[j],       b0r = B[64 + j],  b0n = B[128 + j];
  const float xW0z = W[j]       + b0z, xW1z = W[192 + j] + b0z;
  const float xW0r = W[64 + j]  + b0r, xW1r = W[256 + j] + b0r;
  const float xW0n = W[128 + j] + b0n, xW1n = W[320 + j] + b0n;
  const float wdd = Wd[2*j + 1] - Wd[2*j];   // dense difference column
  const float bdd = Bd[1] - Bd[0];

  float ha = 0.0f, hb_ = 0.0f;
  float logPa = 0.0f, logPb = 0.0f;
  float axz = b0z, axr = b0r, axn = b0n;  // t=0: x=0 -> xm = b[0]
  float bxz = b0z, bxr = b0r, bxn = b0n;
  // loop-carried packed dot accumulators {chain a, chain b}; h_{-1}=0 -> 0
  v2f hz2 = {0.f, 0.f}, hr2 = {0.f, 0.f}, hn2 = {0.f, 0.f};

  for (int t = 0; t < NSTEP; ++t) {
    // ---- r20: keep-alive pins all 192 U values in real VGPRs. The asm
    // nominally writes them, so rematerializing the global loads inside the
    // loop is illegal. Emits ZERO instructions. ----
    asm("" : "+v"(uz0), "+v"(uz1), "+v"(uz2), "+v"(uz3),
             "+v"(ur0), "+v"(ur1), "+v"(ur2), "+v"(ur3),
             "+v"(un0), "+v"(un1), "+v"(un2), "+v"(un3));

    // ---- gates from the PREVIOUS iteration's dot (software pipeline) ----
    {
      const float az = axz + (hz2.x + b1z), ar = axr + (hr2.x + b1r);
      const float zz = fsig(az), rr = fsig(ar);
      const float hh = ftanh(axn + rr * (hn2.x + b1n));
      ha = zz * ha + (1.0f - zz) * hh;
    }
    {
      const float az = bxz + (hz2.y + b1z), ar = bxr + (hr2.y + b1r);
      const float zz = fsig(az), rr = fsig(ar);
      const float hh = ftanh(bxn + rr * (hn2.y + b1n));
      hb_ = zz * hb_ + (1.0f - zz) * hh;
    }
    hsh2[j] = float2{ha, hb_};   // single wave: LDS ops in program order

    // ---- dense: difference-reduction, butterfly m=1..32. Levels 1-8 via
    // DPP VALU (bit-exact), 16/32 via shfl. ----
    float da = ha * wdd, db = hb_ * wdd;
    da = dpp_add<DPP_XOR1>(da); db = dpp_add<DPP_XOR1>(db);
    da = dpp_add<DPP_XOR2>(da); db = dpp_add<DPP_XOR2>(db);
    da = dpp_add<DPP_XOR4>(da); db = dpp_add<DPP_XOR4>(db);
    da = dpp_add<DPP_XOR8>(da); db = dpp_add<DPP_XOR8>(db);
    da += __shfl_xor(da, 16, 64); db += __shfl_xor(db, 16, 64);
    da += __shfl_xor(da, 32, 64); db += __shfl_xor(db, 32, 64);

    int sma, smb;
    {
      const float d = da + bdd;
      const float p1 = fsig(d), p0 = fsig(-d);
      const float lp0 = __logf(1e-10f + p0);
      const float lp1 = __logf(1e-10f + p1);
      const float g0 = gsh[2*t], g1 = gsh[2*t + 1];
      sma = (lp1 + g1) > (lp0 + g0);
      logPa += sma ? lp1 : lp0;
      axz = sma ? xW1z : xW0z;
      axr = sma ? xW1r : xW0r;
      axn = sma ? xW1n : xW0n;
    }
    {
      const float d = db + bdd;
      const float p1 = fsig(d), p0 = fsig(-d);
      const float lp0 = __logf(1e-10f + p0);
      const float lp1 = __logf(1e-10f + p1);
      const float g0 = gsh[288 + 2*t], g1 = gsh[288 + 2*t + 1];
      smb = (lp1 + g1) > (lp0 + g0);
      logPb += smb ? lp1 : lp0;
      bxz = smb ? xW1z : xW0z;
      bxr = smb ? xW1r : xW0r;
      bxn = smb ? xW1n : xW0n;
    }
    if (j == 0) {
      out[(s_base + 0) * NSTEP + t] = sma ? 1.0f : 0.0f;
      out[(s_base + 1) * NSTEP + t] = smb ? 1.0f : 0.0f;
    }

    // ---- dot for NEXT step: hm = h_t @ U, k-ascending per half, packed
    // {a,b}. h pairs from LDS float2 broadcast; ALL U operands from regs.
    // Same values, same per-half order as r19 -> bit-identical decisions. ----
    hz2 = v2f{0.f, 0.f}; hr2 = v2f{0.f, 0.f}; hn2 = v2f{0.f, 0.f};
#define DOTC(uzv, urv, unv, blk, cc) \
    { const int c_ = (blk)*4 + (cc); \
      const v4f hA = *(const v4f*)&hsh2[c_*4]; \
      const v4f hB = *(const v4f*)&hsh2[c_*4 + 2]; \
      const v2f h0  = __builtin_shufflevector(hA, hA, 0, 1); \
      const v2f h1  = __builtin_shufflevector(hA, hA, 2, 3); \
      const v2f h2_ = __builtin_shufflevector(hB, hB, 0, 1); \
      const v2f h3  = __builtin_shufflevector(hB, hB, 2, 3); \
      const v2f uz01 = __builtin_shufflevector(uzv, uzv, (cc)*4 + 0, (cc)*4 + 1); \
      const v2f uz23 = __builtin_shufflevector(uzv, uzv, (cc)*4 + 2, (cc)*4 + 3); \
      const v2f ur01 = __builtin_shufflevector(urv, urv, (cc)*4 + 0, (cc)*4 + 1); \
      const v2f ur23 = __builtin_shufflevector(urv, urv, (cc)*4 + 2, (cc)*4 + 3); \
      const v2f un01 = __builtin_shufflevector(unv, unv, (cc)*4 + 0, (cc)*4 + 1); \
      const v2f un23 = __builtin_shufflevector(unv, unv, (cc)*4 + 2, (cc)*4 + 3); \
      PKFMA_LO(hz2, h0,  uz01) PKFMA_LO(hr2, h0,  ur01) PKFMA_LO(hn2, h0,  un01) \
      PKFMA_HI(hz2, h1,  uz01) PKFMA_HI(hr2, h1,  ur01) PKFMA_HI(hn2, h1,  un01) \
      PKFMA_LO(hz2, h2_, uz23) PKFMA_LO(hr2, h2_, ur23) PKFMA_LO(hn2, h2_, un23) \
      PKFMA_HI(hz2, h3,  uz23) PKFMA_HI(hr2, h3,  ur23) PKFMA_HI(hn2, h3,  un23) }
#define DOTBLK(uzv, urv, unv, blk) \
    DOTC(uzv, urv, unv, blk, 0) DOTC(uzv, urv, unv, blk, 1) \
    DOTC(uzv, urv, unv, blk, 2) DOTC(uzv, urv, unv, blk, 3)
    DOTBLK(uz0, ur0, un0, 0)
    DOTBLK(uz1, ur1, un1, 1)
    DOTBLK(uz2, ur2, un2, 2)
    DOTBLK(uz3, ur3, un3, 3)
#undef DOTBLK
#undef DOTC
  }

  if (j == 0) {
    *(float2*)&out[NSAMP * NSTEP + s_base] = float2{logPa, logPb};
  }
}

extern "C" void kernel_launch(void* const* d_in, const int* in_sizes, int n_in,
                              void* d_out, int out_size, void* d_ws, size_t ws_size,
                              hipStream_t stream) {
  // inputs (setup_inputs order): nsamples(1), W(2x192), U(64x192), b(2x192),
  // Wd(64x2), bd(2) — float32
  const float* W  = (const float*)d_in[1];
  const float* U  = (const float*)d_in[2];
  const float* B  = (const float*)d_in[3];
  const float* Wd = (const float*)d_in[4];
  const float* Bd = (const float*)d_in[5];
  vmc_kernel<<<dim3(NSAMP / CPB), dim3(HID), 0, stream>>>(W, U, B, Wd, Bd, (float*)d_out);
}

// Round 6
// 303.736 us; speedup vs baseline: 1.0166x; 1.0166x over previous
//
#include <hip/hip_runtime.h>
#include <cstdint>
#include <math.h>

// GREEN since r6. Ladder: r15 490 -> r17 326 (v_pk_fma_f32 PROVEN full-rate
// on gfx950) -> r19 285 (DPP butterfly). r20 keep-alive = NEUTRAL: VGPR
// stayed 120 -> asm tie does NOT force residency when the value's source is
// a remat-eligible global load.
// ISSUE ARITHMETIC (r20): VALUBusy 72% x 4833cyc/step/SIMD => ~870 VALU
// instr/step/wave; the algorithm itself is ~310 (192 pk-FMA dot + 50 gates
// + 46 decisions + 20 butterfly). ~560 instr/step/wave = U remat loads +
// addr calc + pair-marshalling movs. THE target.
// THIS ROUND r21: launder U through LDS into PRE-PACKED v2f pairs.
//  - one-time per gate: stage {U[2p][col],U[2p+1][col]} into 16KB LDS
//    scratch (coalesced), ds_read_b64 back into 96 v2f register vars.
//  - LDS reads are NOT remattable (buffer overwritten by next gate + asm
//    memory clobber) -> RA must keep 192 floats truly resident (or spill,
//    visible in counters).
//  - each v2f IS the even-aligned pk-FMA broadcast operand -> zero
//    marshalling movs in the loop.
//  - same values, same FMA order, PRNG untouched -> absmax 0.0.
// LDS 20480B -> exactly 8 blocks/CU (as r15), occupancy unchanged.
// Predict: VGPR 120->~240 (success signal; <=256 keeps 2 waves/SIMD), dur
// 290 -> 170-220us, VALUBusy -> 45-60%. Failure: VGPR ~120-180 + dur flat
// => RA spilled -> escalate to asm-def ds_read_b64 next.
// EMPIRICAL RULES: only __launch_bounds__(64,1) gives the full reg budget
// ((64,2)->128 cap, r8 disaster); OccupancyPercent counter is gfx94x
// fallback (untrustworthy). Occupancy is grid-capped at 2 waves/SIMD.
// Locked-in: PRNG = partitionable threefry (key_t = tf((0,42),(0,t)); bits =
// o0^o1 of tf(key_t,(0,2s+cat))); f32 in/out; out = [4096*144][4096];
// decisions rounding-robust (6 arithmetic variants, bit-identical streams).

#define NSAMP 4096
#define NSTEP 144
#define HID 64
#define CPB 2            // chains per block (one wave)

typedef float v4f  __attribute__((ext_vector_type(4)));
typedef float v2f  __attribute__((ext_vector_type(2)));

// ---- JAX threefry2x32 (20 rounds, key-inject every 4) ----
__device__ __forceinline__ void threefry2x32(uint32_t k0, uint32_t k1,
                                             uint32_t x0, uint32_t x1,
                                             uint32_t& o0, uint32_t& o1) {
  const uint32_t ks0 = k0, ks1 = k1, ks2 = k0 ^ k1 ^ 0x1BD11BDAu;
  x0 += ks0; x1 += ks1;
#define TF_ROUND(d) { x0 += x1; x1 = (x1 << (d)) | (x1 >> (32 - (d))); x1 ^= x0; }
  TF_ROUND(13) TF_ROUND(15) TF_ROUND(26) TF_ROUND(6)
  x0 += ks1; x1 += ks2 + 1u;
  TF_ROUND(17) TF_ROUND(29) TF_ROUND(16) TF_ROUND(24)
  x0 += ks2; x1 += ks0 + 2u;
  TF_ROUND(13) TF_ROUND(15) TF_ROUND(26) TF_ROUND(6)
  x0 += ks0; x1 += ks1 + 3u;
  TF_ROUND(17) TF_ROUND(29) TF_ROUND(16) TF_ROUND(24)
  x0 += ks1; x1 += ks2 + 4u;
  TF_ROUND(13) TF_ROUND(15) TF_ROUND(26) TF_ROUND(6)
  x0 += ks2; x1 += ks0 + 5u;
#undef TF_ROUND
  o0 = x0; o1 = x1;
}

// fast branch-free f32 transcendentals (raw v_exp_f32 / v_log_f32 / v_rcp_f32)
__device__ __forceinline__ float fsig(float x) {        // 1/(1+e^-x), stable
  return __builtin_amdgcn_rcpf(1.0f + __expf(-x));
}
__device__ __forceinline__ float ftanh(float x) {       // 1 - 2/(e^2x+1)
  const float e = __expf(2.0f * x);
  return 1.0f - 2.0f * __builtin_amdgcn_rcpf(e + 1.0f);
}

// Packed f32 FMA, chains (a,b) in (lo,hi). u-pair is an even-aligned register
// pair; LO variant broadcasts its low element to both halves, HI the high one.
#define PKFMA_LO(acc, h2, up) \
  asm("v_pk_fma_f32 %0, %1, %2, %0 op_sel_hi:[1,0,1]" \
      : "+v"(acc) : "v"(h2), "v"(up));
#define PKFMA_HI(acc, h2, up) \
  asm("v_pk_fma_f32 %0, %1, %2, %0 op_sel:[0,1,0] op_sel_hi:[1,1,1]" \
      : "+v"(acc) : "v"(h2), "v"(up));

// DPP butterfly level: v += lane-swapped(v). ctrl as template param (imm).
// Patterns bitwise-match __shfl_xor(v, m) given the uniformity at each level.
template <int CTRL>
__device__ __forceinline__ float dpp_add(float v) {
  union { float f; int i; } c; c.f = v;
  union { int i; float f; } r;
  r.i = __builtin_amdgcn_mov_dpp(c.i, CTRL, 0xF, 0xF, true);
  return v + r.f;
}
#define DPP_XOR1 0xB1   // quad_perm(1,0,3,2)
#define DPP_XOR2 0x4E   // quad_perm(2,3,0,1)
#define DPP_XOR4 0x141  // row_half_mirror (quad-uniform => == xor4)
#define DPP_XOR8 0x140  // row_mirror (8-uniform => == xor8)

__global__ __launch_bounds__(64, 1) void vmc_kernel(
    const float* __restrict__ W, const float* __restrict__ U,
    const float* __restrict__ B, const float* __restrict__ Wd,
    const float* __restrict__ Bd, float* __restrict__ out) {
  const int j = threadIdx.x;           // hidden unit owned by this lane
  const int s_base = blockIdx.x * CPB; // first of 2 chains in this block

  __shared__ __align__(16) float2 hsh2[HID];       // h[unit] = {chain a, chain b}
  __shared__ __align__(16) float2 upairs[32 * HID];// 16KB U-pair staging (reused/gate)
  __shared__ uint2 kkeys[NSTEP];
  __shared__ float gsh[CPB * 2 * NSTEP];           // gumbels [c*288 + 2t + cat]

  // --- per-step keys: key_t = threefry((0,42),(0,t)) ---
#pragma unroll 1
  for (int t = j; t < NSTEP; t += HID) {
    uint32_t o0, o1;
    threefry2x32(0u, 42u, 0u, (uint32_t)t, o0, o1);
    kkeys[t].x = o0; kkeys[t].y = o1;
  }
  hsh2[j] = float2{0.0f, 0.0f};
  __syncthreads();

  // --- gumbels: EXACT path kept (f64 libm, one-time): bits = o0^o1 of
  // tf(key_t,(0,2s+cat)); u = bitcast(bits>>9|0x3f800000)-1 clamped tiny ---
#pragma unroll 1
  for (int id = j; id < CPB * 2 * NSTEP; id += HID) {
    const int c = id / 288;
    const int idx = id - c * 288;
    const uint2 kt = kkeys[idx >> 1];
    const uint32_t i = 2u * (uint32_t)(s_base + c) + (uint32_t)(idx & 1);
    uint32_t o0, o1;
    threefry2x32(kt.x, kt.y, 0u, i, o0, o1);
    const uint32_t bits = o0 ^ o1;
    union { uint32_t u; float f; } cv; cv.u = (bits >> 9) | 0x3F800000u;
    float uf = cv.f - 1.0f;
    uf = fmaxf(uf, 1.17549435e-38f);
    const float inner = (float)log((double)uf);
    gsh[id] = -(float)log((double)(-inner));
  }
  __syncthreads();

  // --- U -> 96 register-resident v2f pairs, laundered through LDS so the
  // loads are NOT rematerializable and land pre-packed in even pairs.
  // uq[g*32+p] = {U[2p][g*64+j], U[2p+1][g*64+j]}  (gate g: 0=z, 1=r, 2=n) ---
  v2f uq[96];
#define STAGE_GATE(g) \
  { _Pragma("unroll") \
    for (int p = 0; p < 32; ++p) { \
      float2 w; \
      w.x = U[(2*p + 0) * 192 + (g)*64 + j]; \
      w.y = U[(2*p + 1) * 192 + (g)*64 + j]; \
      upairs[p * HID + j] = w; \
    } \
    __syncthreads(); \
    _Pragma("unroll") \
    for (int p = 0; p < 32; ++p) \
      uq[(g)*32 + p] = *(const v2f*)&upairs[p * HID + j]; \
    __syncthreads(); }
  STAGE_GATE(0)
  STAGE_GATE(1)
  STAGE_GATE(2)
#undef STAGE_GATE
  // LDS-content clobber: after this, re-reading upairs is illegal for the
  // compiler -> uq can never be rematerialized from LDS or global.
  asm volatile("" ::: "memory");

  const float b1z = B[192 + j], b1r = B[256 + j], b1n = B[320 + j];
  const float b0z = B[j],       b0r = B[64 + j],  b0n = B[128 + j];
  const float xW0z = W[j]       + b0z, xW1z = W[192 + j] + b0z;
  const float xW0r = W[64 + j]  + b0r, xW1r = W[256 + j] + b0r;
  const float xW0n = W[128 + j] + b0n, xW1n = W[320 + j] + b0n;
  const float wdd = Wd[2*j + 1] - Wd[2*j];   // dense difference column
  const float bdd = Bd[1] - Bd[0];

  float ha = 0.0f, hb_ = 0.0f;
  float logPa = 0.0f, logPb = 0.0f;
  float axz = b0z, axr = b0r, axn = b0n;  // t=0: x=0 -> xm = b[0]
  float bxz = b0z, bxr = b0r, bxn = b0n;
  // loop-carried packed dot accumulators {chain a, chain b}; h_{-1}=0 -> 0
  v2f hz2 = {0.f, 0.f}, hr2 = {0.f, 0.f}, hn2 = {0.f, 0.f};

  for (int t = 0; t < NSTEP; ++t) {
    // ---- gates from the PREVIOUS iteration's dot (software pipeline) ----
    {
      const float az = axz + (hz2.x + b1z), ar = axr + (hr2.x + b1r);
      const float zz = fsig(az), rr = fsig(ar);
      const float hh = ftanh(axn + rr * (hn2.x + b1n));
      ha = zz * ha + (1.0f - zz) * hh;
    }
    {
      const float az = bxz + (hz2.y + b1z), ar = bxr + (hr2.y + b1r);
      const float zz = fsig(az), rr = fsig(ar);
      const float hh = ftanh(bxn + rr * (hn2.y + b1n));
      hb_ = zz * hb_ + (1.0f - zz) * hh;
    }
    hsh2[j] = float2{ha, hb_};   // single wave: LDS ops in program order

    // ---- dense: difference-reduction, butterfly m=1..32. Levels 1-8 via
    // DPP VALU (bit-exact), 16/32 via shfl. ----
    float da = ha * wdd, db = hb_ * wdd;
    da = dpp_add<DPP_XOR1>(da); db = dpp_add<DPP_XOR1>(db);
    da = dpp_add<DPP_XOR2>(da); db = dpp_add<DPP_XOR2>(db);
    da = dpp_add<DPP_XOR4>(da); db = dpp_add<DPP_XOR4>(db);
    da = dpp_add<DPP_XOR8>(da); db = dpp_add<DPP_XOR8>(db);
    da += __shfl_xor(da, 16, 64); db += __shfl_xor(db, 16, 64);
    da += __shfl_xor(da, 32, 64); db += __shfl_xor(db, 32, 64);

    int sma, smb;
    {
      const float d = da + bdd;
      const float p1 = fsig(d), p0 = fsig(-d);
      const float lp0 = __logf(1e-10f + p0);
      const float lp1 = __logf(1e-10f + p1);
      const float g0 = gsh[2*t], g1 = gsh[2*t + 1];
      sma = (lp1 + g1) > (lp0 + g0);
      logPa += sma ? lp1 : lp0;
      axz = sma ? xW1z : xW0z;
      axr = sma ? xW1r : xW0r;
      axn = sma ? xW1n : xW0n;
    }
    {
      const float d = db + bdd;
      const float p1 = fsig(d), p0 = fsig(-d);
      const float lp0 = __logf(1e-10f + p0);
      const float lp1 = __logf(1e-10f + p1);
      const float g0 = gsh[288 + 2*t], g1 = gsh[288 + 2*t + 1];
      smb = (lp1 + g1) > (lp0 + g0);
      logPb += smb ? lp1 : lp0;
      bxz = smb ? xW1z : xW0z;
      bxr = smb ? xW1r : xW0r;
      bxn = smb ? xW1n : xW0n;
    }
    if (j == 0) {
      out[(s_base + 0) * NSTEP + t] = sma ? 1.0f : 0.0f;
      out[(s_base + 1) * NSTEP + t] = smb ? 1.0f : 0.0f;
    }

    // ---- dot for NEXT step: hm = h_t @ U, k-ascending per half, packed
    // {a,b}. h pairs from LDS float2 broadcast; U operands straight from
    // the 96 resident v2f pairs (zero marshalling). Same values, same
    // per-half order as r19 -> bit-identical decisions. ----
    hz2 = v2f{0.f, 0.f}; hr2 = v2f{0.f, 0.f}; hn2 = v2f{0.f, 0.f};
#define DOTC(c_) \
    { const v4f hA = *(const v4f*)&hsh2[(c_)*4]; \
      const v4f hB = *(const v4f*)&hsh2[(c_)*4 + 2]; \
      const v2f h0  = __builtin_shufflevector(hA, hA, 0, 1); \
      const v2f h1  = __builtin_shufflevector(hA, hA, 2, 3); \
      const v2f h2_ = __builtin_shufflevector(hB, hB, 0, 1); \
      const v2f h3  = __builtin_shufflevector(hB, hB, 2, 3); \
      PKFMA_LO(hz2, h0,  uq[0*32 + 2*(c_)])     PKFMA_LO(hr2, h0,  uq[1*32 + 2*(c_)])     PKFMA_LO(hn2, h0,  uq[2*32 + 2*(c_)]) \
      PKFMA_HI(hz2, h1,  uq[0*32 + 2*(c_)])     PKFMA_HI(hr2, h1,  uq[1*32 + 2*(c_)])     PKFMA_HI(hn2, h1,  uq[2*32 + 2*(c_)]) \
      PKFMA_LO(hz2, h2_, uq[0*32 + 2*(c_) + 1]) PKFMA_LO(hr2, h2_, uq[1*32 + 2*(c_) + 1]) PKFMA_LO(hn2, h2_, uq[2*32 + 2*(c_) + 1]) \
      PKFMA_HI(hz2, h3,  uq[0*32 + 2*(c_) + 1]) PKFMA_HI(hr2, h3,  uq[1*32 + 2*(c_) + 1]) PKFMA_HI(hn2, h3,  uq[2*32 + 2*(c_) + 1]) }
    DOTC(0)  DOTC(1)  DOTC(2)  DOTC(3)
    DOTC(4)  DOTC(5)  DOTC(6)  DOTC(7)
    DOTC(8)  DOTC(9)  DOTC(10) DOTC(11)
    DOTC(12) DOTC(13) DOTC(14) DOTC(15)
#undef DOTC
  }

  if (j == 0) {
    *(float2*)&out[NSAMP * NSTEP + s_base] = float2{logPa, logPb};
  }
}

extern "C" void kernel_launch(void* const* d_in, const int* in_sizes, int n_in,
                              void* d_out, int out_size, void* d_ws, size_t ws_size,
                              hipStream_t stream) {
  // inputs (setup_inputs order): nsamples(1), W(2x192), U(64x192), b(2x192),
  // Wd(64x2), bd(2) — float32
  const float* W  = (const float*)d_in[1];
  const float* U  = (const float*)d_in[2];
  const float* B  = (const float*)d_in[3];
  const float* Wd = (const float*)d_in[4];
  const float* Bd = (const float*)d_in[5];
  vmc_kernel<<<dim3(NSAMP / CPB), dim3(HID), 0, stream>>>(W, U, B, Wd, Bd, (float*)d_out);
}